// Round 1
// baseline (880.992 us; speedup 1.0000x reference)
//
#include <hip/hip_runtime.h>
#include <hip/hip_bf16.h>
#include <stdint.h>

#define B_ 2
#define S_ 2048
#define H_ 32
#define HKV_ 8
#define D_ 128
#define QB 64
#define KVB 32
#define VROWS 40   // V^T row stride in shorts (32 + 8 pad = 80B, multiple of 16B)

typedef __attribute__((ext_vector_type(8))) short bf16x8;
typedef __attribute__((ext_vector_type(4))) float f32x4;

__device__ __forceinline__ short f2bf(float f) {
  union { float f; uint32_t u; } v; v.f = f;
  uint32_t u = v.u;
  u += 0x7fffu + ((u >> 16) & 1u);   // RNE
  return (short)(u >> 16);
}

// ---------------- cache copy + scatter (exact fp32) ----------------

__global__ void cache_copy_kernel(const float4* __restrict__ src,
                                  float4* __restrict__ dst, int n4) {
  int i = blockIdx.x * blockDim.x + threadIdx.x;
  if (i < n4) dst[i] = src[i];
}

__global__ void cache_scatter_kernel(const float4* __restrict__ key,
                                     const float4* __restrict__ val,
                                     const int* __restrict__ bi,
                                     const int* __restrict__ bo,
                                     float4* __restrict__ kc,
                                     float4* __restrict__ vc) {
  int idx = blockIdx.x * blockDim.x + threadIdx.x;  // [0, 4096*256)
  int t = idx >> 8;          // token
  int rem = idx & 255;       // kvh*32 + d4  (256 float4 = 1024 floats per token)
  int slot = bi[t] * 128 + bo[t];
  kc[(int64_t)slot * 256 + rem] = key[(int64_t)t * 256 + rem];
  vc[(int64_t)slot * 256 + rem] = val[(int64_t)t * 256 + rem];
}

// ---------------- fused causal GQA flash attention ----------------
// block = (b, h, 64-row q block); 4 waves, wave w owns q rows [w*16, w*16+16)
// A-fragment (16x16x32): lane holds A[row=l&15][k=(l>>4)*8+j]
// B-fragment:            lane holds B[k=(l>>4)*8+j][col=l&15]
// C/D:                   lane holds D[row=(l>>4)*4+r][col=l&15]

__global__ __launch_bounds__(256)
void attn_kernel(const float* __restrict__ Q, const float* __restrict__ K,
                 const float* __restrict__ V, float* __restrict__ O) {
  __shared__ short Klds[KVB * 128];     // [32][128] bf16, XOR-swizzled
  __shared__ short Vt[128 * VROWS];     // V^T [128][40] bf16 (padded)
  __shared__ short Plds[4 * 16 * 32];   // per-wave P [16][32] bf16, swizzled

  const int bid = blockIdx.x;
  const int qb  = bid & 31;        // q block index
  const int bh  = bid >> 5;
  const int h   = bh & 31;
  const int b   = bh >> 5;
  const int kvh = h >> 2;          // GQA: 4 query heads per kv head

  const int tid = threadIdx.x;
  const int w = tid >> 6;
  const int l = tid & 63;
  const int c = l & 15;
  const int g = l >> 4;

  const float scale = 0.08838834764831845f;  // 1/sqrt(128)

  // ---- Q fragments: 16 rows per wave, K-dim = 128 -> 4 frags ----
  const int qrow = qb * QB + w * 16 + c;
  const float* qptr = Q + ((int64_t)(b * S_ + qrow)) * (H_ * D_) + h * D_;
  bf16x8 qf[4];
#pragma unroll
  for (int f = 0; f < 4; ++f) {
    const int d0 = f * 32 + g * 8;
    float4 a  = *(const float4*)(qptr + d0);
    float4 bb = *(const float4*)(qptr + d0 + 4);
    bf16x8 r;
    r[0] = f2bf(a.x);  r[1] = f2bf(a.y);  r[2] = f2bf(a.z);  r[3] = f2bf(a.w);
    r[4] = f2bf(bb.x); r[5] = f2bf(bb.y); r[6] = f2bf(bb.z); r[7] = f2bf(bb.w);
    qf[f] = r;
  }

  f32x4 acc[8];
#pragma unroll
  for (int i = 0; i < 8; ++i) acc[i] = f32x4{0.f, 0.f, 0.f, 0.f};
  float m_r[4] = {-3e38f, -3e38f, -3e38f, -3e38f};
  float l_r[4] = {0.f, 0.f, 0.f, 0.f};

  const int qmax_w = qb * QB + w * 16 + 15;
  const int nkt = (qb * QB + QB) / KVB;   // 2*qb + 2 full kv tiles

  const float* kbase = K + (int64_t)b * S_ * (HKV_ * D_) + kvh * D_;
  const float* vbase = V + (int64_t)b * S_ * (HKV_ * D_) + kvh * D_;
  short* Pw = Plds + w * (16 * 32);

  for (int kt = 0; kt < nkt; ++kt) {
    const int kv0 = kt * KVB;
    __syncthreads();   // previous tile fully consumed
    // ---- stage K,V tile: 32 keys x 128 d, f32 -> bf16 ----
#pragma unroll
    for (int it = 0; it < 4; ++it) {
      const int idx = tid + it * 256;      // 0..1023 float4 slots
      const int i  = idx >> 5;             // key row 0..31
      const int d0 = (idx & 31) * 4;       // d offset
      const float4 kf = *(const float4*)(kbase + (int64_t)(kv0 + i) * (HKV_ * D_) + d0);
      const float4 vf = *(const float4*)(vbase + (int64_t)(kv0 + i) * (HKV_ * D_) + d0);
      int kaddr = (i * 128 + d0) * 2;
      kaddr ^= (i & 7) << 4;               // bank-conflict swizzle (G4)
      short4 ks;
      ks.x = f2bf(kf.x); ks.y = f2bf(kf.y); ks.z = f2bf(kf.z); ks.w = f2bf(kf.w);
      *(short4*)((char*)Klds + kaddr) = ks;
      Vt[(d0 + 0) * VROWS + i] = f2bf(vf.x);
      Vt[(d0 + 1) * VROWS + i] = f2bf(vf.y);
      Vt[(d0 + 2) * VROWS + i] = f2bf(vf.z);
      Vt[(d0 + 3) * VROWS + i] = f2bf(vf.w);
    }
    __syncthreads();
    if (kv0 > qmax_w) continue;   // fully masked for this wave (barrier stays uniform)

    // ---- QK^T: scores[16 q][32 k] ----
    f32x4 s[2];
    s[0] = f32x4{0.f, 0.f, 0.f, 0.f};
    s[1] = f32x4{0.f, 0.f, 0.f, 0.f};
#pragma unroll
    for (int t = 0; t < 2; ++t) {
      const int kr = t * 16 + c;
#pragma unroll
      for (int f = 0; f < 4; ++f) {
        int kaddr = (kr * 128 + f * 32 + g * 8) * 2;
        kaddr ^= (kr & 7) << 4;
        bf16x8 kfr = *(const bf16x8*)((char*)Klds + kaddr);
        s[t] = __builtin_amdgcn_mfma_f32_16x16x32_bf16(qf[f], kfr, s[t], 0, 0, 0);
      }
    }

    // ---- causal mask + scale ----
    float sv[2][4];
#pragma unroll
    for (int t = 0; t < 2; ++t)
#pragma unroll
      for (int r = 0; r < 4; ++r) {
        const int kvcol = kv0 + t * 16 + c;
        const int qr = qb * QB + w * 16 + g * 4 + r;
        sv[t][r] = (kvcol > qr) ? -1e30f : s[t][r] * scale;
      }

    // ---- online softmax (wave-parallel row reduce over 16-lane groups) ----
    float al[4];
#pragma unroll
    for (int r = 0; r < 4; ++r) {
      float x = fmaxf(sv[0][r], sv[1][r]);
      x = fmaxf(x, __shfl_xor(x, 1));
      x = fmaxf(x, __shfl_xor(x, 2));
      x = fmaxf(x, __shfl_xor(x, 4));
      x = fmaxf(x, __shfl_xor(x, 8));
      const float mn = fmaxf(m_r[r], x);
      al[r] = __expf(m_r[r] - mn);
      m_r[r] = mn;
      const float p0 = __expf(sv[0][r] - mn);
      const float p1 = __expf(sv[1][r] - mn);
      sv[0][r] = p0; sv[1][r] = p1;
      float su = p0 + p1;
      su += __shfl_xor(su, 1);
      su += __shfl_xor(su, 2);
      su += __shfl_xor(su, 4);
      su += __shfl_xor(su, 8);
      l_r[r] = l_r[r] * al[r] + su;
    }

    // ---- P (D-layout) -> LDS -> A-fragment layout ----
#pragma unroll
    for (int t = 0; t < 2; ++t)
#pragma unroll
      for (int r = 0; r < 4; ++r) {
        const int row = g * 4 + r;
        const int col = t * 16 + c;
        int addr = (row * 32 + col) * 2;
        addr ^= (row & 3) << 4;
        *(short*)((char*)Pw + addr) = f2bf(sv[t][r]);
      }
    asm volatile("" ::: "memory");   // keep ds_write before ds_read

    // ---- rescale accumulator ----
#pragma unroll
    for (int dt = 0; dt < 8; ++dt)
#pragma unroll
      for (int r = 0; r < 4; ++r) acc[dt][r] *= al[r];

    // ---- PV: out[16 q][128 d] += P[16][32] * V[32][128] ----
    int paddr = (c * 32 + g * 8) * 2;
    paddr ^= (c & 3) << 4;
    bf16x8 pf = *(const bf16x8*)((char*)Pw + paddr);
#pragma unroll
    for (int dt = 0; dt < 8; ++dt) {
      const int vaddr = ((dt * 16 + c) * VROWS + g * 8) * 2;
      bf16x8 vfr = *(const bf16x8*)((char*)Vt + vaddr);
      acc[dt] = __builtin_amdgcn_mfma_f32_16x16x32_bf16(pf, vfr, acc[dt], 0, 0, 0);
    }
  }

  // ---- epilogue: normalize and store fp32 ----
#pragma unroll
  for (int r = 0; r < 4; ++r) {
    const int qr = qb * QB + w * 16 + g * 4 + r;
    const float inv = 1.f / l_r[r];
    float* optr = O + ((int64_t)(b * S_ + qr)) * (H_ * D_) + h * D_;
#pragma unroll
    for (int dt = 0; dt < 8; ++dt) optr[dt * 16 + c] = acc[dt][r] * inv;
  }
}

extern "C" void kernel_launch(void* const* d_in, const int* in_sizes, int n_in,
                              void* d_out, int out_size, void* d_ws, size_t ws_size,
                              hipStream_t stream) {
  const float* Q   = (const float*)d_in[0];
  const float* K   = (const float*)d_in[1];
  const float* V   = (const float*)d_in[2];
  const float* kvc = (const float*)d_in[3];
  const int*   bi  = (const int*)d_in[4];
  const int*   bo  = (const int*)d_in[5];
  // d_in[6] = attn_bias: exactly the causal mask; applied analytically.

  float* out = (float*)d_out;
  float* kc = out + (int64_t)B_ * S_ * H_ * D_;          // +16777216
  float* vc = kc + (int64_t)128 * 128 * HKV_ * D_;       // +16777216

  // 1) copy both kv_cache planes into the cache output region (contiguous)
  const int n4 = (2 * 128 * 128 * HKV_ * D_) / 4;        // 8388608 float4
  hipLaunchKernelGGL(cache_copy_kernel, dim3((n4 + 255) / 256), dim3(256), 0, stream,
                     (const float4*)kvc, (float4*)kc, n4);
  // 2) scatter the 4096 prefill tokens into the caches
  hipLaunchKernelGGL(cache_scatter_kernel, dim3(4096), dim3(256), 0, stream,
                     (const float4*)K, (const float4*)V, bi, bo,
                     (float4*)kc, (float4*)vc);
  // 3) fused causal GQA attention
  hipLaunchKernelGGL(attn_kernel, dim3(B_ * H_ * (S_ / QB)), dim3(256), 0, stream,
                     Q, K, V, out);
}

// Round 2
// 532.451 us; speedup vs baseline: 1.6546x; 1.6546x over previous
//
#include <hip/hip_runtime.h>
#include <hip/hip_bf16.h>
#include <stdint.h>

#define B_ 2
#define S_ 2048
#define H_ 32
#define HKV_ 8
#define D_ 128
#define QB 128     // q rows per block (8 waves x 16)
#define KVB 64     // kv rows per staged tile
#define VROWS 68   // V^T row stride in shorts (136B: 4-way write / 2-way read)

typedef __attribute__((ext_vector_type(8))) short bf16x8;
typedef __attribute__((ext_vector_type(4))) float f32x4;

__device__ __forceinline__ short f2bf(float f) {
  union { float f; uint32_t u; } v; v.f = f;
  uint32_t u = v.u;
  u += 0x7fffu + ((u >> 16) & 1u);   // RNE
  return (short)(u >> 16);
}

// ---------------- cache copy + scatter (exact fp32) ----------------

__global__ void cache_copy_kernel(const float4* __restrict__ src,
                                  float4* __restrict__ dst, int n4) {
  int i = blockIdx.x * blockDim.x + threadIdx.x;
  if (i < n4) dst[i] = src[i];
}

__global__ void cache_scatter_kernel(const float4* __restrict__ key,
                                     const float4* __restrict__ val,
                                     const int* __restrict__ bi,
                                     const int* __restrict__ bo,
                                     float4* __restrict__ kc,
                                     float4* __restrict__ vc) {
  int idx = blockIdx.x * blockDim.x + threadIdx.x;  // [0, 4096*256)
  int t = idx >> 8;
  int rem = idx & 255;
  int slot = bi[t] * 128 + bo[t];
  kc[(int64_t)slot * 256 + rem] = key[(int64_t)t * 256 + rem];
  vc[(int64_t)slot * 256 + rem] = val[(int64_t)t * 256 + rem];
}

// ---------------- fused causal GQA flash attention ----------------
// block = (b, h, 128-row q block); 8 waves, wave w owns q rows [w*16, w*16+16)
// A-frag (16x16x32): lane holds A[row=l&15][k=(l>>4)*8+j]
// B-frag:            lane holds B[k=(l>>4)*8+j][col=l&15]
// C/D:               lane holds D[row=(l>>4)*4+r][col=l&15]

__global__ __launch_bounds__(512, 4)
void attn_kernel(const float* __restrict__ Q, const float* __restrict__ K,
                 const float* __restrict__ V, float* __restrict__ O) {
  __shared__ short Klds[KVB * 128];      // 16 KB, XOR-swizzled rows
  __shared__ short Vt[128 * VROWS];      // 17408 B, V^T
  __shared__ short Plds[8 * 16 * 32];    // 8 KB, per-wave P chunk

  const int bid = blockIdx.x;
  const int qb  = 15 - (bid & 15);       // LPT: long blocks dispatched first
  const int bh  = bid >> 4;
  const int h   = bh & 31;
  const int b   = bh >> 5;
  const int kvh = h >> 2;

  const int tid = threadIdx.x;
  const int w = tid >> 6;
  const int l = tid & 63;
  const int c = l & 15;
  const int g = l >> 4;

  const float scale = 0.08838834764831845f;  // 1/sqrt(128) folded into Q

  // ---- Q fragments (16 rows/wave, 4 k-slices of 32) ----
  const int qrow = qb * QB + w * 16 + c;
  const float* qptr = Q + ((int64_t)(b * S_ + qrow)) * (H_ * D_) + h * D_;
  bf16x8 qf[4];
#pragma unroll
  for (int f = 0; f < 4; ++f) {
    const int d0 = f * 32 + g * 8;
    float4 a  = *(const float4*)(qptr + d0);
    float4 bb = *(const float4*)(qptr + d0 + 4);
    bf16x8 r;
    r[0] = f2bf(a.x * scale);  r[1] = f2bf(a.y * scale);
    r[2] = f2bf(a.z * scale);  r[3] = f2bf(a.w * scale);
    r[4] = f2bf(bb.x * scale); r[5] = f2bf(bb.y * scale);
    r[6] = f2bf(bb.z * scale); r[7] = f2bf(bb.w * scale);
    qf[f] = r;
  }

  f32x4 acc[8];
#pragma unroll
  for (int i = 0; i < 8; ++i) acc[i] = f32x4{0.f, 0.f, 0.f, 0.f};
  float m_r[4] = {-3e38f, -3e38f, -3e38f, -3e38f};
  float l_r[4] = {0.f, 0.f, 0.f, 0.f};

  const int base = qb * QB + w * 16;     // wave's min q row
  const int qmax_w = base + 15;
  const int nkt = (qb + 1) * (QB / KVB);

  const float* kbase = K + (int64_t)b * S_ * (HKV_ * D_) + kvh * D_;
  const float* vbase = V + (int64_t)b * S_ * (HKV_ * D_) + kvh * D_;
  short* Pw = Plds + w * (16 * 32);

  // V staging map: thread -> column d, 16 consecutive kv rows
  const int vd  = tid & 127;
  const int kvb = (tid >> 7) * 16;

  for (int kt = 0; kt < nkt; ++kt) {
    const int kv0 = kt * KVB;
    __syncthreads();   // previous tile fully consumed

    // ---- stage K: 64 rows x 128 d, float4 loads -> short4 swizzled ----
#pragma unroll
    for (int it = 0; it < 4; ++it) {
      const int idx = tid + it * 512;        // 0..2047 float4 slots
      const int i  = idx >> 5;               // key row 0..63
      const int d0 = (idx & 31) * 4;
      const float4 kf = *(const float4*)(kbase + (int64_t)(kv0 + i) * (HKV_ * D_) + d0);
      int kaddr = (i * 128 + d0) * 2;
      kaddr ^= (i & 7) << 4;
      short4 ks;
      ks.x = f2bf(kf.x); ks.y = f2bf(kf.y); ks.z = f2bf(kf.z); ks.w = f2bf(kf.w);
      *(short4*)((char*)Klds + kaddr) = ks;
    }
    // ---- stage V^T: lane=d coalesced loads, short4 row writes ----
#pragma unroll
    for (int i = 0; i < 4; ++i) {
      short4 st;
      st.x = f2bf(vbase[(int64_t)(kv0 + kvb + 4 * i + 0) * (HKV_ * D_) + vd]);
      st.y = f2bf(vbase[(int64_t)(kv0 + kvb + 4 * i + 1) * (HKV_ * D_) + vd]);
      st.z = f2bf(vbase[(int64_t)(kv0 + kvb + 4 * i + 2) * (HKV_ * D_) + vd]);
      st.w = f2bf(vbase[(int64_t)(kv0 + kvb + 4 * i + 3) * (HKV_ * D_) + vd]);
      *(short4*)(Vt + vd * VROWS + kvb + 4 * i) = st;
    }
    __syncthreads();
    if (kv0 > qmax_w) continue;   // fully masked for this wave

    // ---- QK^T: scores[16 q][64 k] ----
    f32x4 s[4];
#pragma unroll
    for (int t = 0; t < 4; ++t) s[t] = f32x4{0.f, 0.f, 0.f, 0.f};
#pragma unroll
    for (int t = 0; t < 4; ++t) {
      const int kr = t * 16 + c;
#pragma unroll
      for (int f = 0; f < 4; ++f) {
        int kaddr = (kr * 128 + f * 32 + g * 8) * 2;
        kaddr ^= (kr & 7) << 4;
        bf16x8 kfr = *(const bf16x8*)((char*)Klds + kaddr);
        s[t] = __builtin_amdgcn_mfma_f32_16x16x32_bf16(qf[f], kfr, s[t], 0, 0, 0);
      }
    }

    // ---- causal mask (only needed on the wave-boundary tile) ----
    float sv[4][4];
    const bool needmask = (kv0 + (KVB - 1) > base);
#pragma unroll
    for (int t = 0; t < 4; ++t)
#pragma unroll
      for (int r = 0; r < 4; ++r) {
        float val = s[t][r];
        if (needmask && (kv0 + t * 16 + c > base + g * 4 + r)) val = -1e30f;
        sv[t][r] = val;
      }

    // ---- online softmax (16-lane-group butterflies) ----
    float al[4];
#pragma unroll
    for (int r = 0; r < 4; ++r) {
      float x = fmaxf(fmaxf(sv[0][r], sv[1][r]), fmaxf(sv[2][r], sv[3][r]));
      x = fmaxf(x, __shfl_xor(x, 1));
      x = fmaxf(x, __shfl_xor(x, 2));
      x = fmaxf(x, __shfl_xor(x, 4));
      x = fmaxf(x, __shfl_xor(x, 8));
      const float mn = fmaxf(m_r[r], x);
      al[r] = __expf(m_r[r] - mn);
      m_r[r] = mn;
      float su = 0.f;
#pragma unroll
      for (int t = 0; t < 4; ++t) {
        const float p = __expf(sv[t][r] - mn);
        sv[t][r] = p;
        su += p;
      }
      su += __shfl_xor(su, 1);
      su += __shfl_xor(su, 2);
      su += __shfl_xor(su, 4);
      su += __shfl_xor(su, 8);
      l_r[r] = l_r[r] * al[r] + su;
    }

    // ---- rescale accumulator ----
#pragma unroll
    for (int dt = 0; dt < 8; ++dt)
#pragma unroll
      for (int r = 0; r < 4; ++r) acc[dt][r] *= al[r];

    // ---- PV in two 32-key chunks through per-wave P LDS ----
#pragma unroll
    for (int ks = 0; ks < 2; ++ks) {
#pragma unroll
      for (int t2 = 0; t2 < 2; ++t2)
#pragma unroll
        for (int r = 0; r < 4; ++r) {
          const int row = g * 4 + r;
          const int col = t2 * 16 + c;
          int addr = (row * 32 + col) * 2;
          addr ^= ((row ^ (row >> 2)) & 3) << 4;   // conflict-free write/read pair
          *(short*)((char*)Pw + addr) = f2bf(sv[2 * ks + t2][r]);
        }
      asm volatile("" ::: "memory");
      int paddr = (c * 32 + g * 8) * 2;
      paddr ^= ((c ^ (c >> 2)) & 3) << 4;
      bf16x8 pf = *(const bf16x8*)((char*)Pw + paddr);
#pragma unroll
      for (int dt = 0; dt < 8; ++dt) {
        const short* vp = Vt + (dt * 16 + c) * VROWS + ks * 32 + g * 8;
        short4 lo = *(const short4*)vp;
        short4 hi = *(const short4*)(vp + 4);
        bf16x8 vfr;
        vfr[0] = lo.x; vfr[1] = lo.y; vfr[2] = lo.z; vfr[3] = lo.w;
        vfr[4] = hi.x; vfr[5] = hi.y; vfr[6] = hi.z; vfr[7] = hi.w;
        acc[dt] = __builtin_amdgcn_mfma_f32_16x16x32_bf16(pf, vfr, acc[dt], 0, 0, 0);
      }
      asm volatile("" ::: "memory");
    }
  }

  // ---- epilogue: normalize, store fp32 ----
#pragma unroll
  for (int r = 0; r < 4; ++r) {
    const int qr = base + g * 4 + r;
    const float inv = 1.f / l_r[r];
    float* optr = O + ((int64_t)(b * S_ + qr)) * (H_ * D_) + h * D_;
#pragma unroll
    for (int dt = 0; dt < 8; ++dt) optr[dt * 16 + c] = acc[dt][r] * inv;
  }
}

extern "C" void kernel_launch(void* const* d_in, const int* in_sizes, int n_in,
                              void* d_out, int out_size, void* d_ws, size_t ws_size,
                              hipStream_t stream) {
  const float* Q   = (const float*)d_in[0];
  const float* K   = (const float*)d_in[1];
  const float* V   = (const float*)d_in[2];
  const float* kvc = (const float*)d_in[3];
  const int*   bi  = (const int*)d_in[4];
  const int*   bo  = (const int*)d_in[5];
  // d_in[6] = attn_bias: exactly the causal mask; applied analytically.

  float* out = (float*)d_out;
  float* kc = out + (int64_t)B_ * S_ * H_ * D_;
  float* vc = kc + (int64_t)128 * 128 * HKV_ * D_;

  const int n4 = (2 * 128 * 128 * HKV_ * D_) / 4;
  hipLaunchKernelGGL(cache_copy_kernel, dim3((n4 + 255) / 256), dim3(256), 0, stream,
                     (const float4*)kvc, (float4*)kc, n4);
  hipLaunchKernelGGL(cache_scatter_kernel, dim3(4096), dim3(256), 0, stream,
                     (const float4*)K, (const float4*)V, bi, bo,
                     (float4*)kc, (float4*)vc);
  hipLaunchKernelGGL(attn_kernel, dim3(B_ * H_ * (S_ / QB)), dim3(512), 0, stream,
                     Q, K, V, out);
}

// Round 3
// 442.451 us; speedup vs baseline: 1.9912x; 1.2034x over previous
//
#include <hip/hip_runtime.h>
#include <hip/hip_bf16.h>
#include <stdint.h>

#define B_ 2
#define S_ 2048
#define H_ 32
#define HKV_ 8
#define D_ 128

#define KTILE_SH 16384      // shorts per K tile image (128 keys x 128 d)
#define VROWS 136           // V^T row stride in shorts (272B = 17x16B, conflict-free)
#define VTILE_SH 17408      // 128 * 136
#define PSTRIDE 40          // P chunk row stride in shorts (80B: 16B-aligned rows, bank-bijective)

typedef __attribute__((ext_vector_type(8))) short bf16x8;
typedef __attribute__((ext_vector_type(16))) float f32x16;

typedef const __attribute__((address_space(1))) void gv_t;
typedef __attribute__((address_space(3))) void lv_t;

__device__ __forceinline__ short f2bf(float f) {
  __hip_bfloat16 h = __float2bfloat16(f);   // RNE; compiler can pair into v_cvt_pk_bf16_f32
  union { __hip_bfloat16 h; short s; } u; u.h = h; return u.s;
}

// ---------------- cache copy + scatter (exact fp32) ----------------

__global__ void cache_copy_kernel(const float4* __restrict__ src,
                                  float4* __restrict__ dst, int n4) {
  int i = blockIdx.x * blockDim.x + threadIdx.x;
  if (i < n4) dst[i] = src[i];
}

__global__ void cache_scatter_kernel(const float4* __restrict__ key,
                                     const float4* __restrict__ val,
                                     const int* __restrict__ bi,
                                     const int* __restrict__ bo,
                                     float4* __restrict__ kc,
                                     float4* __restrict__ vc) {
  int idx = blockIdx.x * blockDim.x + threadIdx.x;  // [0, 4096*256)
  int t = idx >> 8;
  int rem = idx & 255;
  int slot = bi[t] * 128 + bo[t];
  kc[(int64_t)slot * 256 + rem] = key[(int64_t)t * 256 + rem];
  vc[(int64_t)slot * 256 + rem] = val[(int64_t)t * 256 + rem];
}

// ---------------- prep: K,V f32 -> bf16 pre-swizzled LDS images ----------------
// K image per (b,kvh,kt): short idx = (key*128 + d) ^ ((key&7)<<3)   [byte XOR (key&7)<<4]
// V image per (b,kvh,kt): V^T [d=128][key padded to 136]

__global__ __launch_bounds__(512)
void prep_kernel(const float* __restrict__ K, const float* __restrict__ V,
                 short* __restrict__ kimg, short* __restrict__ vimg) {
  __shared__ float Vf[128 * 132];
  const int tile = blockIdx.x;          // (b*8+kvh)*16 + kt
  const int kt   = tile & 15;
  const int bkvh = tile >> 4;
  const int kvh  = bkvh & 7;
  const int b    = bkvh >> 3;
  const int tid  = threadIdx.x;
  const int kv0  = kt * 128;
  const float* kb = K + (int64_t)b * S_ * (HKV_ * D_) + kvh * D_;
  const float* vb = V + (int64_t)b * S_ * (HKV_ * D_) + kvh * D_;
  short* kimg_t = kimg + (int64_t)tile * KTILE_SH;
  short* vimg_t = vimg + (int64_t)tile * VTILE_SH;
#pragma unroll
  for (int i = 0; i < 8; ++i) {
    int idx = i * 512 + tid;            // 0..4095 float4 slots
    int key = idx >> 5;
    int d0  = (idx & 31) * 4;
    float4 kf = *(const float4*)(kb + (int64_t)(kv0 + key) * (HKV_ * D_) + d0);
    float4 vf = *(const float4*)(vb + (int64_t)(kv0 + key) * (HKV_ * D_) + d0);
    short4 ks;
    ks.x = f2bf(kf.x); ks.y = f2bf(kf.y); ks.z = f2bf(kf.z); ks.w = f2bf(kf.w);
    int koff = (key * 128 + d0) ^ ((key & 7) << 3);
    *(short4*)(kimg_t + koff) = ks;
    *(float4*)(Vf + key * 132 + d0) = vf;
  }
  __syncthreads();
  const int d  = tid & 127;
  const int kg = tid >> 7;              // 4 groups of 32 keys
#pragma unroll
  for (int j2 = 0; j2 < 4; ++j2) {
    int k0 = kg * 32 + j2 * 8;
    short4 a, bq;
    a.x  = f2bf(Vf[(k0 + 0) * 132 + d]); a.y  = f2bf(Vf[(k0 + 1) * 132 + d]);
    a.z  = f2bf(Vf[(k0 + 2) * 132 + d]); a.w  = f2bf(Vf[(k0 + 3) * 132 + d]);
    bq.x = f2bf(Vf[(k0 + 4) * 132 + d]); bq.y = f2bf(Vf[(k0 + 5) * 132 + d]);
    bq.z = f2bf(Vf[(k0 + 6) * 132 + d]); bq.w = f2bf(Vf[(k0 + 7) * 132 + d]);
    *(short4*)(vimg_t + d * VROWS + k0)     = a;
    *(short4*)(vimg_t + d * VROWS + k0 + 4) = bq;
  }
}

// ---------------- fused causal GQA flash attention ----------------
// block = (b, kvh, 64 q positions) x 4 heads; 8 waves; wave = (head=w&3, rowgroup=w>>2)
// 32x32x16 MFMA. A: row=l&31, k=(l>>5)*8+j. B: col=l&31, k=(l>>5)*8+j.
// C/D: col=l&31, row=(r&3)+8*(r>>2)+4*(l>>5).

__global__ __launch_bounds__(512, 2)
void attn_kernel(const float* __restrict__ Q, const short* __restrict__ kimg,
                 const short* __restrict__ vimg, float* __restrict__ O) {
  __shared__ short Kl[2][KTILE_SH];       // 2 x 32 KB
  __shared__ short Vl[2][VTILE_SH];       // 2 x 34 KB
  __shared__ short Pc[8][32 * PSTRIDE];   // 8 x 2.5 KB

  const int bid = blockIdx.x;
  const int hg  = bid & 15;               // (b,kvh)
  const int c   = 31 - (bid >> 4);        // LPT: big chunks first
  const int kvh = hg & 7;
  const int b   = hg >> 3;

  const int tid = threadIdx.x;
  const int w   = tid >> 6;
  const int l   = tid & 63;
  const int c31 = l & 31;
  const int hi  = l >> 5;
  const int head = w & 3;
  const int rg   = w >> 2;
  const int h    = kvh * 4 + head;
  const int qbase = c * 64 + rg * 32;

  // ---- Q fragments: 32 rows/wave, 8 k-slices of 16 ----
  const float scale = 0.08838834764831845f;  // 1/sqrt(128) folded into Q
  const float* qp = Q + ((int64_t)(b * S_ + qbase + c31)) * (H_ * D_) + h * D_;
  bf16x8 qf[8];
#pragma unroll
  for (int ks = 0; ks < 8; ++ks) {
    int d0 = ks * 16 + hi * 8;
    float4 x = *(const float4*)(qp + d0);
    float4 y = *(const float4*)(qp + d0 + 4);
    bf16x8 r;
    r[0] = f2bf(x.x * scale); r[1] = f2bf(x.y * scale);
    r[2] = f2bf(x.z * scale); r[3] = f2bf(x.w * scale);
    r[4] = f2bf(y.x * scale); r[5] = f2bf(y.y * scale);
    r[6] = f2bf(y.z * scale); r[7] = f2bf(y.w * scale);
    qf[ks] = r;
  }

  f32x16 acc[4];
#pragma unroll
  for (int dt = 0; dt < 4; ++dt)
#pragma unroll
    for (int r = 0; r < 16; ++r) acc[dt][r] = 0.f;
  float m_r[16], l_r[16];
#pragma unroll
  for (int r = 0; r < 16; ++r) { m_r[r] = -3e38f; l_r[r] = 0.f; }

  const int nkt = (c >> 1) + 1;
  const short* kimg_b = kimg + (int64_t)(hg * 16) * KTILE_SH;
  const short* vimg_b = vimg + (int64_t)(hg * 16) * VTILE_SH;
  short* Pw = &Pc[w][0];

#define STAGE(KT)                                                              \
  do {                                                                         \
    const short* kg_ = kimg_b + (int64_t)(KT) * KTILE_SH;                      \
    const short* vg_ = vimg_b + (int64_t)(KT) * VTILE_SH;                      \
    short* kl_ = &Kl[(KT) & 1][0];                                             \
    short* vl_ = &Vl[(KT) & 1][0];                                             \
    _Pragma("unroll")                                                          \
    for (int i_ = 0; i_ < 4; ++i_) {                                           \
      int u_ = i_ * 512 + w * 64;                                              \
      __builtin_amdgcn_global_load_lds((gv_t*)(const void*)(kg_ + (u_ + l) * 8), \
                                       (lv_t*)(void*)(kl_ + u_ * 8), 16, 0, 0); \
    }                                                                          \
    _Pragma("unroll")                                                          \
    for (int i_ = 0; i_ < 5; ++i_) {                                           \
      int u_ = i_ * 512 + w * 64;                                              \
      if (u_ < 2176) {                                                         \
        __builtin_amdgcn_global_load_lds((gv_t*)(const void*)(vg_ + (u_ + l) * 8), \
                                         (lv_t*)(void*)(vl_ + u_ * 8), 16, 0, 0); \
      }                                                                        \
    }                                                                          \
  } while (0)

  STAGE(0);

  for (int kt = 0; kt < nkt; ++kt) {
    __syncthreads();                 // drains vmcnt: buf[kt] ready; prev buf consumed
    if (kt + 1 < nkt) STAGE(kt + 1); // prefetch overlaps compute below
    const short* kl = &Kl[kt & 1][0];
    const short* vl = &Vl[kt & 1][0];
    const int kv0 = kt << 7;
    const bool lasttile = (kv0 + 127 > qbase);
    const int active = lasttile ? (((qbase + 31 - kv0) >> 5) + 1) : 4;

    // ---- QK^T: S[32 q][128 k] as 4 col-tiles ----
    f32x16 s[4];
#pragma unroll
    for (int t = 0; t < 4; ++t) {
      if (t < active) {
        f32x16 sv;
#pragma unroll
        for (int r = 0; r < 16; ++r) sv[r] = 0.f;
        const int key = t * 32 + c31;
#pragma unroll
        for (int ks = 0; ks < 8; ++ks) {
          int koff = (key * 128 + ks * 16 + hi * 8) ^ ((key & 7) << 3);
          bf16x8 kf = *(const bf16x8*)(kl + koff);
          sv = __builtin_amdgcn_mfma_f32_32x32x16_bf16(qf[ks], kf, sv, 0, 0, 0);
        }
        s[t] = sv;
      }
    }

    // ---- mask / inactive init ----
#pragma unroll
    for (int t = 0; t < 4; ++t) {
      if (t >= active) {
#pragma unroll
        for (int r = 0; r < 16; ++r) s[t][r] = -1e30f;
      } else if (lasttile) {
#pragma unroll
        for (int r = 0; r < 16; ++r) {
          int crow = (r & 3) + 8 * (r >> 2) + hi * 4;
          if (kv0 + t * 32 + c31 > qbase + crow) s[t][r] = -1e30f;
        }
      }
    }

    // ---- online softmax (row = 32 lanes of one half-wave) ----
    float al[16];
#pragma unroll
    for (int r = 0; r < 16; ++r) {
      float x = fmaxf(fmaxf(s[0][r], s[1][r]), fmaxf(s[2][r], s[3][r]));
      x = fmaxf(x, __shfl_xor(x, 1));
      x = fmaxf(x, __shfl_xor(x, 2));
      x = fmaxf(x, __shfl_xor(x, 4));
      x = fmaxf(x, __shfl_xor(x, 8));
      x = fmaxf(x, __shfl_xor(x, 16));
      const float mn = fmaxf(m_r[r], x);
      al[r] = __expf(m_r[r] - mn);
      m_r[r] = mn;
      float su = 0.f;
#pragma unroll
      for (int t = 0; t < 4; ++t) {
        float p = __expf(s[t][r] - mn);
        s[t][r] = p;
        su += p;
      }
      su += __shfl_xor(su, 1);
      su += __shfl_xor(su, 2);
      su += __shfl_xor(su, 4);
      su += __shfl_xor(su, 8);
      su += __shfl_xor(su, 16);
      l_r[r] = l_r[r] * al[r] + su;
    }

    // ---- rescale accumulator ----
#pragma unroll
    for (int dt = 0; dt < 4; ++dt)
#pragma unroll
      for (int r = 0; r < 16; ++r) acc[dt][r] *= al[r];

    // ---- PV: per 32-key chunk, D-layout -> A-layout via per-wave LDS ----
#pragma unroll
    for (int t = 0; t < 4; ++t) {
      if (t < active) {
#pragma unroll
        for (int r = 0; r < 16; ++r) {
          int crow = (r & 3) + 8 * (r >> 2) + hi * 4;
          Pw[crow * PSTRIDE + c31] = f2bf(s[t][r]);
        }
        asm volatile("" ::: "memory");
#pragma unroll
        for (int ks2 = 0; ks2 < 2; ++ks2) {
          bf16x8 pf = *(const bf16x8*)(Pw + c31 * PSTRIDE + ks2 * 16 + hi * 8);
#pragma unroll
          for (int dt = 0; dt < 4; ++dt) {
            const short* vp = vl + (dt * 32 + c31) * VROWS + t * 32 + ks2 * 16 + hi * 8;
            bf16x8 vf = *(const bf16x8*)vp;
            acc[dt] = __builtin_amdgcn_mfma_f32_32x32x16_bf16(pf, vf, acc[dt], 0, 0, 0);
          }
        }
        asm volatile("" ::: "memory");
      }
    }
  }

  // ---- epilogue: normalize, store fp32 ----
  float* ob = O + (int64_t)(b * S_) * (H_ * D_) + h * D_;
#pragma unroll
  for (int r = 0; r < 16; ++r) {
    int crow = (r & 3) + 8 * (r >> 2) + hi * 4;
    float inv = 1.f / l_r[r];
    float* orow = ob + (int64_t)(qbase + crow) * (H_ * D_);
#pragma unroll
    for (int dt = 0; dt < 4; ++dt) orow[dt * 32 + c31] = acc[dt][r] * inv;
  }
#undef STAGE
}

extern "C" void kernel_launch(void* const* d_in, const int* in_sizes, int n_in,
                              void* d_out, int out_size, void* d_ws, size_t ws_size,
                              hipStream_t stream) {
  const float* Q   = (const float*)d_in[0];
  const float* K   = (const float*)d_in[1];
  const float* V   = (const float*)d_in[2];
  const float* kvc = (const float*)d_in[3];
  const int*   bi  = (const int*)d_in[4];
  const int*   bo  = (const int*)d_in[5];
  // d_in[6] = attn_bias: exactly the causal mask; applied analytically.

  float* out = (float*)d_out;
  float* kc = out + (int64_t)B_ * S_ * H_ * D_;
  float* vc = kc + (int64_t)128 * 128 * HKV_ * D_;

  short* kimg = (short*)d_ws;                                   // 256 tiles * 32 KB
  short* vimg = kimg + (int64_t)256 * KTILE_SH;                 // 256 tiles * 34 KB

  hipLaunchKernelGGL(prep_kernel, dim3(256), dim3(512), 0, stream, K, V, kimg, vimg);
  hipLaunchKernelGGL(attn_kernel, dim3(512), dim3(512), 0, stream, Q, kimg, vimg, out);

  const int n4 = (2 * 128 * 128 * HKV_ * D_) / 4;
  hipLaunchKernelGGL(cache_copy_kernel, dim3((n4 + 255) / 256), dim3(256), 0, stream,
                     (const float4*)kvc, (float4*)kc, n4);
  hipLaunchKernelGGL(cache_scatter_kernel, dim3(4096), dim3(256), 0, stream,
                     (const float4*)K, (const float4*)V, bi, bo,
                     (float4*)kc, (float4*)vc);
}

// Round 4
// 168.822 us; speedup vs baseline: 5.2185x; 2.6208x over previous
//
#include <hip/hip_runtime.h>
#include <hip/hip_bf16.h>
#include <stdint.h>

#define B_ 2
#define S_ 2048
#define HKV_ 8
#define D_ 128

#define KVB 32
#define KTILE_SH 4096        // 32 keys x 128 d shorts (8 KB)
#define VROWS 40             // V^T row stride in shorts (80 B, 16B-aligned, minimal-conflict)
#define VTILE_SH 5120        // 128 * 40 shorts (10240 B)
#define LDSBUF 18432         // bytes per staging buffer (K 8192 + V 10240)

typedef __attribute__((ext_vector_type(8))) short bf16x8;
typedef __attribute__((ext_vector_type(16))) float f32x16;
typedef __attribute__((ext_vector_type(4))) int int4v;

typedef const __attribute__((address_space(1))) void gv_t;
typedef __attribute__((address_space(3))) void lv_t;

__device__ __forceinline__ unsigned pk2(float lo, float hi) {
  unsigned r;
  asm("v_cvt_pk_bf16_f32 %0, %1, %2" : "=v"(r) : "v"(lo), "v"(hi));
  return r;
}
__device__ __forceinline__ void plswap(unsigned& a, unsigned& b) {
  asm volatile("v_permlane32_swap_b32 %0, %1" : "+v"(a), "+v"(b));
}
__device__ __forceinline__ bf16x8 frag4(unsigned a, unsigned b, unsigned c, unsigned d) {
  union { int4v i; bf16x8 v; } u;
  u.i = int4v{(int)a, (int)b, (int)c, (int)d};
  return u.v;
}

// ---------------- cache copy (exact fp32) ----------------

__global__ void cache_copy_kernel(const float4* __restrict__ src,
                                  float4* __restrict__ dst, int n4) {
  int i = blockIdx.x * blockDim.x + threadIdx.x;
  if (i < n4) dst[i] = src[i];
}

// ------- prep: K,V f32 -> bf16 pre-swizzled images + cache scatter -------
// K image per tile: short idx = key*128 + (d ^ ((key&7)<<3))
// V image per tile: V^T [d=128][key padded to 40]

__global__ __launch_bounds__(256)
void prep_kernel(const float* __restrict__ K, const float* __restrict__ V,
                 const int* __restrict__ bi, const int* __restrict__ bo,
                 float* __restrict__ kc, float* __restrict__ vc,
                 short* __restrict__ kimg, short* __restrict__ vimg) {
  __shared__ float Vf[KVB * 132];
  const int bid = blockIdx.x;
  const int hg  = bid & 15;          // (b,kvh) -> keeps each XCD on 2 images
  const int kt  = bid >> 4;          // 0..63
  const int kvh = hg & 7;
  const int b   = hg >> 3;
  const int tid = threadIdx.x;
  const int kv0 = kt * KVB;
  const float* kb = K + (int64_t)b * S_ * 1024 + kvh * 128;
  const float* vb = V + (int64_t)b * S_ * 1024 + kvh * 128;
  short* kimg_t = kimg + (int64_t)(hg * 64 + kt) * KTILE_SH;
  short* vimg_t = vimg + (int64_t)(hg * 64 + kt) * VTILE_SH;
#pragma unroll
  for (int i = 0; i < 4; ++i) {
    int idx = i * 256 + tid;         // 0..1023 float4 slots
    int key = idx >> 5;              // 0..31
    int d0  = (idx & 31) * 4;
    int64_t roff = (int64_t)(kv0 + key) * 1024 + d0;
    float4 kf = *(const float4*)(kb + roff);
    float4 vf = *(const float4*)(vb + roff);
    // cache scatter (exact fp32)
    int tok = b * S_ + kv0 + key;
    int64_t slot = (int64_t)bi[tok] * 128 + bo[tok];
    *(float4*)(kc + slot * 1024 + kvh * 128 + d0) = kf;
    *(float4*)(vc + slot * 1024 + kvh * 128 + d0) = vf;
    // K image, pre-swizzled
    unsigned k01 = pk2(kf.x, kf.y), k23 = pk2(kf.z, kf.w);
    int koff = key * 128 + (d0 ^ ((key & 7) << 3));
    int2 st; st.x = (int)k01; st.y = (int)k23;
    *(int2*)(kimg_t + koff) = st;
    *(float4*)(&Vf[key * 132 + d0]) = vf;
  }
  __syncthreads();
  const int d  = tid & 127;
  const int kg = tid >> 7;           // 0..1, 16 keys each
  const int k0 = kg * 16;
  unsigned uu[8];
#pragma unroll
  for (int i2 = 0; i2 < 8; ++i2)
    uu[i2] = pk2(Vf[(k0 + 2 * i2) * 132 + d], Vf[(k0 + 2 * i2 + 1) * 132 + d]);
  *(int4v*)(vimg_t + d * VROWS + k0)     = int4v{(int)uu[0], (int)uu[1], (int)uu[2], (int)uu[3]};
  *(int4v*)(vimg_t + d * VROWS + k0 + 8) = int4v{(int)uu[4], (int)uu[5], (int)uu[6], (int)uu[7]};
}

// ---------------- fused causal GQA flash attention ----------------
// block = (b,kvh, 32 q rows) x 4 heads; 4 waves; wave covers 2 heads x 16 q as
// the 32 MFMA columns (col = hh*16 + qi). Swapped MFMAs:
//   S^T = mfma(K, Q^T): lane owns col = one (head,q); softmax lane-local.
//   O^T = mfma(V^T, P^T): acc col = same (head,q) -> scalar per-lane rescale.
// C/D: col=l&31, row=(r&3)+8*(r>>2)+4*(l>>5).

__global__ __launch_bounds__(256, 3)
void attn_kernel(const float* __restrict__ Q, const short* __restrict__ kimg,
                 const short* __restrict__ vimg, float* __restrict__ O) {
  __shared__ int4v ldsv[2 * LDSBUF / 16];
  char* ldsb = (char*)ldsv;

  const int bid = blockIdx.x;
  const int hg  = bid & 15;
  const int cc  = 63 - (bid >> 4);   // LPT: longest q-chunks first
  const int kvh = hg & 7;
  const int b   = hg >> 3;

  const int tid = threadIdx.x;
  const int w   = tid >> 6;
  const int l   = tid & 63;
  const int c31 = l & 31;
  const int hi  = l >> 5;
  const int qi  = c31 & 15;
  const int hh  = c31 >> 4;
  const int qoff = cc * 32 + (w & 1) * 16;
  const int qrow = qoff + qi;
  const int h    = kvh * 4 + (w >> 1) * 2 + hh;
  const int sw   = (c31 & 7) << 3;

  const float qscale = 0.08838834764831845f * 1.4426950408889634f; // 1/sqrt(D) * log2e

  // ---- Q fragments (B-frag: col = (head,q), k = d-slice) ----
  const float* qp = Q + ((int64_t)(b * S_ + qrow)) * 4096 + h * 128;
  bf16x8 qf[8];
#pragma unroll
  for (int ks = 0; ks < 8; ++ks) {
    int d0 = ks * 16 + hi * 8;
    float4 x = *(const float4*)(qp + d0);
    float4 y = *(const float4*)(qp + d0 + 4);
    qf[ks] = frag4(pk2(x.x * qscale, x.y * qscale), pk2(x.z * qscale, x.w * qscale),
                   pk2(y.x * qscale, y.y * qscale), pk2(y.z * qscale, y.w * qscale));
  }

  f32x16 acc[4];
#pragma unroll
  for (int dt = 0; dt < 4; ++dt)
#pragma unroll
    for (int r = 0; r < 16; ++r) acc[dt][r] = 0.f;
  float m = -1e30f, lsum = 0.f;

  const int nkt = cc + 1;
  const short* kimg_b = kimg + (int64_t)(hg * 64) * KTILE_SH;
  const short* vimg_b = vimg + (int64_t)(hg * 64) * VTILE_SH;

#define STAGE(KT, BUF)                                                          \
  do {                                                                          \
    const short* kg_ = kimg_b + (int64_t)(KT) * KTILE_SH;                       \
    const short* vg_ = vimg_b + (int64_t)(KT) * VTILE_SH;                       \
    char* kd_ = ldsb + (BUF) * LDSBUF;                                          \
    char* vd_ = kd_ + 8192;                                                     \
    _Pragma("unroll")                                                           \
    for (int i_ = 0; i_ < 2; ++i_) {                                            \
      int u_ = i_ * 256 + w * 64;                                               \
      __builtin_amdgcn_global_load_lds((gv_t*)(const void*)(kg_ + (u_ + l) * 8),\
                                       (lv_t*)(void*)(kd_ + u_ * 16), 16, 0, 0);\
    }                                                                           \
    _Pragma("unroll")                                                           \
    for (int i_ = 0; i_ < 3; ++i_) {                                            \
      int u_ = i_ * 256 + w * 64;                                               \
      if (u_ < 640) {                                                           \
        __builtin_amdgcn_global_load_lds((gv_t*)(const void*)(vg_ + (u_ + l) * 8),\
                                         (lv_t*)(void*)(vd_ + u_ * 16), 16, 0, 0);\
      }                                                                         \
    }                                                                           \
  } while (0)

  STAGE(0, 0);

  for (int kt = 0; kt < nkt; ++kt) {
    __syncthreads();                  // drains vmcnt: buf[kt&1] ready, buf[(kt+1)&1] free
    const int cur = kt & 1;
    if (kt + 1 < nkt) STAGE(kt + 1, cur ^ 1);
    const short* kl = (const short*)(ldsb + cur * LDSBUF);
    const short* vl = (const short*)(ldsb + cur * LDSBUF + 8192);
    const int kv0 = kt * KVB;

    // ---- S^T = K . Q^T  (lane col = its (head,q)) ----
    f32x16 s;
#pragma unroll
    for (int r = 0; r < 16; ++r) s[r] = 0.f;
#pragma unroll
    for (int ks = 0; ks < 8; ++ks) {
      int koff = c31 * 128 + ((ks * 16 + hi * 8) ^ sw);
      bf16x8 kf = *(const bf16x8*)(kl + koff);
      s = __builtin_amdgcn_mfma_f32_32x32x16_bf16(kf, qf[ks], s, 0, 0, 0);
    }

    // ---- causal mask (boundary tiles only) ----
    if (kv0 + 31 > qoff) {
#pragma unroll
      for (int r = 0; r < 16; ++r) {
        int key = kv0 + (r & 3) + 8 * (r >> 2) + 4 * hi;
        if (key > qrow) s[r] = -1e30f;
      }
    }

    // ---- lane-local online softmax (log2 domain, defer-max THR=11) ----
    float qm = s[0];
#pragma unroll
    for (int r = 1; r < 16; ++r) qm = fmaxf(qm, s[r]);
    qm = fmaxf(qm, __shfl_xor(qm, 32));      // sync with partner lane (same q)
    if (__any(qm > m + 11.0f)) {
      float mn = fmaxf(m, qm);
      float al = exp2f(m - mn);
      m = mn; lsum *= al;
#pragma unroll
      for (int dt = 0; dt < 4; ++dt)
#pragma unroll
        for (int r = 0; r < 16; ++r) acc[dt][r] *= al;
    }
    float su = 0.f;
#pragma unroll
    for (int r = 0; r < 16; ++r) {
      float p = exp2f(s[r] - m);
      s[r] = p;
      su += p;
    }
    lsum += su;

    // ---- P -> bf16 B-frags via cvt_pk + permlane32_swap (no LDS) ----
    unsigned u0 = pk2(s[0], s[1]),  u1 = pk2(s[2], s[3]);
    unsigned u2 = pk2(s[4], s[5]),  u3 = pk2(s[6], s[7]);
    unsigned u4 = pk2(s[8], s[9]),  u5 = pk2(s[10], s[11]);
    unsigned u6 = pk2(s[12], s[13]), u7 = pk2(s[14], s[15]);
    plswap(u0, u2); plswap(u1, u3);          // keys 0..15
    plswap(u4, u6); plswap(u5, u7);          // keys 16..31
    bf16x8 pf0 = frag4(u0, u1, u2, u3);
    bf16x8 pf1 = frag4(u4, u5, u6, u7);

    // ---- O^T += V^T . P^T ----
#pragma unroll
    for (int ks2 = 0; ks2 < 2; ++ks2) {
      bf16x8 pf = ks2 ? pf1 : pf0;
#pragma unroll
      for (int dt = 0; dt < 4; ++dt) {
        const short* vp = vl + (dt * 32 + c31) * VROWS + ks2 * 16 + hi * 8;
        bf16x8 vf = *(const bf16x8*)vp;
        acc[dt] = __builtin_amdgcn_mfma_f32_32x32x16_bf16(vf, pf, acc[dt], 0, 0, 0);
      }
    }
  }
#undef STAGE

  // ---- epilogue: combine partner l, transpose O^T -> O via LDS, store ----
  float lt = lsum + __shfl_xor(lsum, 32);
  float inv = 1.0f / lt;
  __syncthreads();                           // staging buffers dead now
  float* scr = (float*)ldsb + w * (32 * 33);
  float* ob = O + (int64_t)(b * S_) * 4096;
#pragma unroll
  for (int dt = 0; dt < 4; ++dt) {
#pragma unroll
    for (int r = 0; r < 16; ++r) {
      int crow = (r & 3) + 8 * (r >> 2) + 4 * hi;
      scr[c31 * 33 + crow] = acc[dt][r] * inv;   // scr[col][d']
    }
    asm volatile("" ::: "memory");
#pragma unroll
    for (int rr = 0; rr < 16; ++rr) {
      int col = rr * 2 + hi;
      float val = scr[col * 33 + c31];
      int qi2 = col & 15, hh2 = col >> 4;
      int qq = cc * 32 + (w & 1) * 16 + qi2;
      int h2 = kvh * 4 + (w >> 1) * 2 + hh2;
      ob[(int64_t)qq * 4096 + h2 * 128 + dt * 32 + c31] = val;
    }
    asm volatile("" ::: "memory");
  }
}

extern "C" void kernel_launch(void* const* d_in, const int* in_sizes, int n_in,
                              void* d_out, int out_size, void* d_ws, size_t ws_size,
                              hipStream_t stream) {
  const float* Q   = (const float*)d_in[0];
  const float* K   = (const float*)d_in[1];
  const float* V   = (const float*)d_in[2];
  const float* kvc = (const float*)d_in[3];
  const int*   bi  = (const int*)d_in[4];
  const int*   bo  = (const int*)d_in[5];
  // d_in[6] = attn_bias: exactly the causal mask; applied analytically.

  float* out = (float*)d_out;
  float* kc = out + (int64_t)B_ * S_ * 32 * 128;         // +16777216
  float* vc = kc + (int64_t)128 * 128 * HKV_ * D_;       // +16777216

  short* kimg = (short*)d_ws;                            // 1024 tiles * 8 KB
  short* vimg = kimg + (int64_t)1024 * KTILE_SH;         // 1024 tiles * 10 KB

  // 1) copy kv_cache planes (scatter in prep overwrites the prefill slots)
  const int n4 = (2 * 128 * 128 * HKV_ * D_) / 4;        // 8388608 float4
  hipLaunchKernelGGL(cache_copy_kernel, dim3(n4 / 256), dim3(256), 0, stream,
                     (const float4*)kvc, (float4*)kc, n4);
  // 2) bf16 pre-swizzled K/V images + cache scatter
  hipLaunchKernelGGL(prep_kernel, dim3(1024), dim3(256), 0, stream,
                     K, V, bi, bo, kc, vc, kimg, vimg);
  // 3) fused causal GQA attention
  hipLaunchKernelGGL(attn_kernel, dim3(1024), dim3(256), 0, stream,
                     Q, kimg, vimg, out);
}